// Round 2
// baseline (8773.695 us; speedup 1.0000x reference)
//
#include <hip/hip_runtime.h>
#include <stdint.h>

// GRU: B=128, T=1024, D=512, H=512, C=2. gates [z,r,h], reset_after=True.
// Strategy: one persistent kernel, 256 wgs x 192 thr (3 waves = 3 gates).
// Each wg owns a [16 b-rows x 16 hidden-cols] tile. W,R fragments in VGPRs.
// Per step: stage h (fp32->bf16 LDS, swizzled), mfma h@R, gate math fp32,
// write h_new via agent-scope write-through stores, per-step counter barrier,
// overlap x_{t+1}@W mfma with the barrier wait.

#define NWG   256
#define WB    8
#define BT    192
#define Tseq  1024
#define Bdim  128
#define Ddim  512
#define Hdim  512
#define NH3   1536

typedef __attribute__((ext_vector_type(8))) short short8;
typedef __attribute__((ext_vector_type(4))) float f32x4;

union U4S8 { uint4 u; short8 s; };

__device__ __forceinline__ unsigned short f2bf(float f) {
  unsigned u = __float_as_uint(f);
  unsigned r = (u + 0x7FFFu + ((u >> 16) & 1u)) >> 16;  // RNE
  return (unsigned short)r;
}
__device__ __forceinline__ unsigned pack2(float a, float b) {
  return (unsigned)f2bf(a) | ((unsigned)f2bf(b) << 16);
}
__device__ __forceinline__ float bsig(float x) { return 1.f / (1.f + __expf(-x)); }
__device__ __forceinline__ float btanh(float x) {
  float a = fabsf(x);
  float e = __expf(-2.f * a);
  float t = (1.f - e) / (1.f + e);
  return x < 0.f ? -t : t;
}

// Stage 16 rows x 512 floats -> LDS bf16 [16][512], XOR-swizzled (G4: row-major
// stride-1KB rows are a bank conflict on ds_read_b128; byte ^= (row&7)<<4).
__device__ __forceinline__ void stage16x512(unsigned short* lds, const float* src,
                                            size_t rowStride, int tid) {
  for (int c = tid; c < 1024; c += BT) {
    int row = c >> 6, cb = c & 63;
    const float* p = src + (size_t)row * rowStride + (size_t)cb * 8;
    float4 a = *(const float4*)p;
    float4 b = *(const float4*)(p + 4);
    uint4 v;
    v.x = pack2(a.x, a.y); v.y = pack2(a.z, a.w);
    v.z = pack2(b.x, b.y); v.w = pack2(b.z, b.w);
    int byte = (row << 10) | (((cb << 4) ^ ((row & 7) << 4)));
    *(uint4*)((char*)lds + byte) = v;
  }
}

// A-fragment for mfma_f32_16x16x32_bf16: lane l holds A[l&15][(l>>4)*8 + j].
__device__ __forceinline__ short8 readA(const unsigned short* lds, int lane, int kk) {
  int row = lane & 15, kg = lane >> 4;
  int byte = (row << 10) | ((((kk << 6) + (kg << 4)) ^ ((row & 7) << 4)));
  U4S8 t;
  t.u = *(const uint4*)((const char*)lds + byte);
  return t.s;
}

__global__ __launch_bounds__(BT) void gru_persist(
    const float* __restrict__ x, const float* __restrict__ W,
    const float* __restrict__ R, const float* __restrict__ b_i,
    const float* __restrict__ b_r, int* __restrict__ cnt,
    float* __restrict__ h0, float* __restrict__ h1) {
  __shared__ alignas(16) unsigned short hA[16 * 512];
  __shared__ alignas(16) unsigned short xA[16 * 512];
  __shared__ float tg[4][256];  // pre_z, pre_r, xh+bi, hp+br

  const int tid  = threadIdx.x;
  const int lane = tid & 63;
  const int g    = tid >> 6;                 // wave = gate 0:z 1:r 2:h
  const int wb   = blockIdx.x & (WB - 1);
  const int wj   = blockIdx.x >> 3;
  const int brow0 = wb << 4;
  const int col0  = wj << 4;
  const int colL  = lane & 15;
  const int kg    = lane >> 4;
  const int gc    = g * Hdim + col0 + colL;  // column in [0,1536)

  // ---- one-time: B-fragments of W and R into VGPRs ----
  // B-frag: lane l holds M[kk*32 + (l>>4)*8 + j][col0 + (l&15)].
  short8 Wf_[16], Rf_[16];
#pragma unroll
  for (int kk = 0; kk < 16; ++kk) {
    short8 w, r;
#pragma unroll
    for (int j = 0; j < 8; ++j) {
      int k = kk * 32 + kg * 8 + j;
      w[j] = (short)f2bf(W[(size_t)k * NH3 + gc]);
      r[j] = (short)f2bf(R[(size_t)k * NH3 + gc]);
    }
    Wf_[kk] = w; Rf_[kk] = r;
  }
  const float bi = b_i[gc];
  const float br = b_r[gc];

  // ---- prologue: xp for t=0 ----
  stage16x512(xA, x + (size_t)brow0 * (Tseq * Ddim), (size_t)Tseq * Ddim, tid);
  __syncthreads();
  f32x4 accX = {0.f, 0.f, 0.f, 0.f};
#pragma unroll
  for (int kk = 0; kk < 16; ++kk)
    accX = __builtin_amdgcn_mfma_f32_16x16x32_bf16(readA(xA, lane, kk), Wf_[kk], accX, 0, 0, 0);

  for (int t = 0; t < Tseq; ++t) {
    const float* hin  = (t & 1) ? h1 : h0;
    float*       hout = (t & 1) ? h0 : h1;

    // stage h_t (fp32 global -> bf16 LDS)
    stage16x512(hA, hin + (size_t)brow0 * Hdim, (size_t)Hdim, tid);
    __syncthreads();

    // hp = h_t @ R   (this wave's gate columns)
    f32x4 accH = {0.f, 0.f, 0.f, 0.f};
#pragma unroll
    for (int kk = 0; kk < 16; ++kk)
      accH = __builtin_amdgcn_mfma_f32_16x16x32_bf16(readA(hA, lane, kk), Rf_[kk], accH, 0, 0, 0);

    // exchange gate tiles (D layout: row=(l>>4)*4+r, col=l&15)
#pragma unroll
    for (int r4 = 0; r4 < 4; ++r4) {
      int e = ((kg * 4 + r4) << 4) | colL;
      if (g == 0)      tg[0][e] = accX[r4] + accH[r4] + bi + br;
      else if (g == 1) tg[1][e] = accX[r4] + accH[r4] + bi + br;
      else {           tg[2][e] = accX[r4] + bi;
                       tg[3][e] = accH[r4] + br; }
    }
    __syncthreads();

    // elementwise gates + h_new (fp32 carry path); write-through agent stores
    for (int e2 = tid; e2 < 128; e2 += BT) {
      int row = e2 >> 3;
      int col = (e2 & 7) << 1;
      int ez  = (row << 4) | col;
      float z0 = bsig(tg[0][ez]),     z1 = bsig(tg[0][ez + 1]);
      float r0 = bsig(tg[1][ez]),     r1 = bsig(tg[1][ez + 1]);
      float hh0 = btanh(tg[2][ez]     + r0 * tg[3][ez]);
      float hh1 = btanh(tg[2][ez + 1] + r1 * tg[3][ez + 1]);
      size_t idx = (size_t)(brow0 + row) * Hdim + col0 + col;
      float ho0 = hin[idx], ho1 = hin[idx + 1];
      union { float f[2]; unsigned long long u; } pk;
      pk.f[0] = z0 * ho0 + (1.f - z0) * hh0;
      pk.f[1] = z1 * ho1 + (1.f - z1) * hh1;
      __hip_atomic_store((unsigned long long*)&hout[idx], pk.u,
                         __ATOMIC_RELAXED, __HIP_MEMORY_SCOPE_AGENT);
    }
    __syncthreads();  // drains vmcnt: all agent stores acked (coherent) before arrive

    if (tid == 0)
      __hip_atomic_fetch_add(&cnt[t], 1, __ATOMIC_RELAXED, __HIP_MEMORY_SCOPE_AGENT);

    // overlap with barrier wait: xp for t+1 (independent of h)
    int tt = (t + 1 < Tseq) ? t + 1 : Tseq - 1;
    stage16x512(xA, x + (size_t)brow0 * (Tseq * Ddim) + (size_t)tt * Ddim,
                (size_t)Tseq * Ddim, tid);
    __syncthreads();
    accX = (f32x4){0.f, 0.f, 0.f, 0.f};
#pragma unroll
    for (int kk = 0; kk < 16; ++kk)
      accX = __builtin_amdgcn_mfma_f32_16x16x32_bf16(readA(xA, lane, kk), Wf_[kk], accX, 0, 0, 0);

    if (tid == 0) {
      while (__hip_atomic_load(&cnt[t], __ATOMIC_RELAXED, __HIP_MEMORY_SCOPE_AGENT) < NWG) {}
      __builtin_amdgcn_fence(__ATOMIC_ACQUIRE, "agent");  // inv L1/L2 before reading h_{t+1}
    }
    __syncthreads();
  }
}

__global__ __launch_bounds__(64) void logits_kernel(const float* __restrict__ hbuf,
                                                    const float* __restrict__ Wf,
                                                    const float* __restrict__ bf,
                                                    float* __restrict__ out) {
  int b = blockIdx.x, l = threadIdx.x;
  const float* hr = hbuf + (size_t)b * Hdim;
  float c0 = 0.f, c1 = 0.f;
#pragma unroll
  for (int i = 0; i < 8; ++i) {
    int k = l * 8 + i;
    float h = hr[k];
    c0 += h * Wf[k * 2 + 0];
    c1 += h * Wf[k * 2 + 1];
  }
  for (int off = 32; off > 0; off >>= 1) {
    c0 += __shfl_down(c0, off);
    c1 += __shfl_down(c1, off);
  }
  if (l == 0) {
    out[b * 2 + 0] = c0 + bf[0];
    out[b * 2 + 1] = c1 + bf[1];
  }
}

extern "C" void kernel_launch(void* const* d_in, const int* in_sizes, int n_in,
                              void* d_out, int out_size, void* d_ws, size_t ws_size,
                              hipStream_t stream) {
  (void)in_sizes; (void)n_in; (void)out_size; (void)ws_size;
  const float* x   = (const float*)d_in[0];
  const float* W   = (const float*)d_in[1];
  const float* R   = (const float*)d_in[2];
  const float* b_i = (const float*)d_in[3];
  const float* b_r = (const float*)d_in[4];
  const float* Wf  = (const float*)d_in[5];
  const float* bf  = (const float*)d_in[6];

  char* ws = (char*)d_ws;
  int*   cnt = (int*)ws;                               // 1024 counters (4 KB)
  float* h0  = (float*)(ws + 4096);                    // h parity-0 (256 KB), holds h_0=0 and finally h_T
  float* h1  = (float*)(ws + 4096 + Bdim * Hdim * 4);  // h parity-1

  // zero counters + h0 (ws is poisoned 0xAA before every launch)
  hipMemsetAsync(ws, 0, 4096 + Bdim * Hdim * 4, stream);

  hipLaunchKernelGGL(gru_persist, dim3(NWG), dim3(BT), 0, stream,
                     x, W, R, b_i, b_r, cnt, h0, h1);
  // T=1024 even -> final h lands in parity-0 buffer
  hipLaunchKernelGGL(logits_kernel, dim3(Bdim), dim3(64), 0, stream,
                     h0, Wf, bf, (float*)d_out);
}